// Round 8
// baseline (447.102 us; speedup 1.0000x reference)
//
#include <hip/hip_runtime.h>
#include <hip/hip_bf16.h>
#include <stdint.h>
#include <math.h>

// Problem constants (fixed by the reference)
#define BATCH 2
#define S_LEN 4096
#define DMODEL 1024
#define NH 16
#define DHEAD 64
#define MTOK (BATCH * S_LEN)  // 8192

// exp(score/8) == exp2(score * 0.125*log2(e)); the 0.18033688 is folded into
// the Q-projection GEMM epilogue so flash's inner loop is exp2 + add only.
#define QSCALE 0.1803368801111793f

typedef unsigned short u16;
typedef __attribute__((ext_vector_type(8))) short bf16x8;  // 8 bf16 = 4 VGPRs
typedef __attribute__((ext_vector_type(4))) float f32x4;
typedef __attribute__((ext_vector_type(4))) unsigned short u16x4;
typedef __attribute__((ext_vector_type(2))) unsigned int u32x2;

__device__ __forceinline__ float b2f(u16 u) {
  union { unsigned int i; float f; } v; v.i = ((unsigned int)u) << 16; return v.f;
}
__device__ __forceinline__ u16 f2b(float f) {
  union { float f; unsigned int i; } v; v.f = f;
  unsigned int r = v.i + 0x7FFF + ((v.i >> 16) & 1);  // RNE
  return (u16)(r >> 16);
}
// pack two f32 into (bf16_trunc(hi)<<16)|bf16_trunc(lo) with one v_perm_b32
__device__ __forceinline__ unsigned int pk2(float hi, float lo) {
  union { float f; unsigned int u; } a, b; a.f = hi; b.f = lo;
  return __builtin_amdgcn_perm(a.u, b.u, 0x07060302u);
}

// async global->LDS, 16B per lane; LDS dest is wave-uniform base (HW adds lane*16).
__device__ __forceinline__ void gl_lds16(const u16* g, u16* l) {
  __builtin_amdgcn_global_load_lds(
      (__attribute__((address_space(1))) void*)(u16*)g,
      (__attribute__((address_space(3))) void*)l, 16, 0, 0);
}

// ---------------------------------------------------------------------------
// Input dtype detection (bf16 vs f32 buffers) — statistical, see round 4.
// flag = 1 -> bf16; flag = 0 -> f32.
// ---------------------------------------------------------------------------
__global__ void detect_dtype(const unsigned int* __restrict__ x, int* __restrict__ flag) {
  __shared__ int cnt;
  if (threadIdx.x == 0) cnt = 0;
  __syncthreads();
  int c = 0;
  for (int i = threadIdx.x; i < 4096; i += 256) {
    unsigned int w = x[i];
    int e = (w >> 7) & 0xFF;  // bf16 exponent field of the low u16
    if (e >= 100 && e <= 135) c++;
  }
  atomicAdd(&cnt, c);
  __syncthreads();
  if (threadIdx.x == 0) *flag = (cnt > 2048) ? 1 : 0;
}

// ---------------------------------------------------------------------------
// Canonicalize x -> bf16. 8192 blocks x 256 threads x 4 elems = 8,388,608.
// ---------------------------------------------------------------------------
__global__ void convert_x(const void* __restrict__ xin, u16* __restrict__ xc,
                          const int* __restrict__ flagp) {
  const int isb = *flagp;
  long e = ((long)blockIdx.x * 256 + threadIdx.x) * 4;
  if (isb) {
    *(uint2*)&xc[e] = *(const uint2*)((const u16*)xin + e);  // 8B copy
  } else {
    float4 f = *(const float4*)((const float*)xin + e);
    xc[e + 0] = f2b(f.x);
    xc[e + 1] = f2b(f.y);
    xc[e + 2] = f2b(f.z);
    xc[e + 3] = f2b(f.w);
  }
}

// ---------------------------------------------------------------------------
// Weight transpose + dtype conversion: out[n*1024+k] = bf16(W[k*1024+n])
// ---------------------------------------------------------------------------
__global__ void transpose4(const void* __restrict__ W0, const void* __restrict__ W1,
                           const void* __restrict__ W2, const void* __restrict__ W3,
                           u16* __restrict__ out, const int* __restrict__ flagp) {
  __shared__ u16 tile[32][33];
  const int isb = *flagp;
  int z = blockIdx.z;
  const void* W = (z == 0) ? W0 : (z == 1) ? W1 : (z == 2) ? W2 : W3;
  u16* o = out + (long)z * (DMODEL * DMODEL);
  int x = blockIdx.x * 32 + threadIdx.x;
  int y0 = blockIdx.y * 32;
  if (isb) {
    const u16* Wb = (const u16*)W;
#pragma unroll
    for (int i = 0; i < 32; i += 8)
      tile[threadIdx.y + i][threadIdx.x] = Wb[(long)(y0 + threadIdx.y + i) * DMODEL + x];
  } else {
    const float* Wf = (const float*)W;
#pragma unroll
    for (int i = 0; i < 32; i += 8)
      tile[threadIdx.y + i][threadIdx.x] = f2b(Wf[(long)(y0 + threadIdx.y + i) * DMODEL + x]);
  }
  __syncthreads();
  int x2 = blockIdx.y * 32 + threadIdx.x;
  int y2 = blockIdx.x * 32;
#pragma unroll
  for (int i = 0; i < 32; i += 8)
    o[(long)(y2 + threadIdx.y + i) * DMODEL + x2] = tile[threadIdx.x][threadIdx.y + i];
}

// ---------------------------------------------------------------------------
// C = scal * (A[M,K] @ Bt[N,K]^T)  (m97: 128x128, BK=32, global_load_lds x16)
// MODE 0: out  (dtype per flag), + bias (dtype per flag)
// MODE 1: scatter bf16 to [B,H,S,DH]   (Q and K; Q gets scal=QSCALE)
// MODE 2: scatter bf16 to [B,H,DH,S]   (V transposed)
// ---------------------------------------------------------------------------
#define BM 128
#define BN 128
#define BK 32

template <int MODE>
__global__ __launch_bounds__(256)
void gemm_bt(const u16* __restrict__ A, const u16* __restrict__ Bt,
             const void* __restrict__ bias, void* __restrict__ C,
             int M, int N, int Kd, const int* __restrict__ flagp, float scal) {
  __shared__ __align__(16) u16 lA[BM * BK];
  __shared__ __align__(16) u16 lB[BN * BK];
  const int tid = threadIdx.x;
  const int w = tid >> 6;
  const int lane = tid & 63;
  const int m0 = blockIdx.y * BM;
  const int n0 = blockIdx.x * BN;
  const int wm = (w >> 1) * 64;
  const int wn = (w & 1) * 64;
  const int lc = lane & 15;
  const int lq = lane >> 4;

  f32x4 acc[4][4] = {};

  for (int k0 = 0; k0 < Kd; k0 += BK) {
    __syncthreads();  // previous tile fully consumed
#pragma unroll
    for (int jj = 0; jj < 2; ++jj) {
      int base = (jj * 4 + w) * 512;  // wave-uniform LDS base (u16 elems)
      int e = base + lane * 8;        // this lane's element (16B per lane)
      int row = e >> 5, col = e & 31;
      gl_lds16(A + (long)(m0 + row) * Kd + k0 + col, lA + base);
      gl_lds16(Bt + (long)(n0 + row) * Kd + k0 + col, lB + base);
    }
    __syncthreads();  // drains vmcnt before consumption

    bf16x8 af[4], bg[4];
#pragma unroll
    for (int i = 0; i < 4; ++i)
      af[i] = *(const bf16x8*)&lA[(wm + i * 16 + lc) * BK + lq * 8];
#pragma unroll
    for (int j = 0; j < 4; ++j)
      bg[j] = *(const bf16x8*)&lB[(wn + j * 16 + lc) * BK + lq * 8];
#pragma unroll
    for (int i = 0; i < 4; ++i)
#pragma unroll
      for (int j = 0; j < 4; ++j)
        acc[i][j] = __builtin_amdgcn_mfma_f32_16x16x32_bf16(af[i], bg[j], acc[i][j], 0, 0, 0);
  }

  // Epilogue: C/D layout col=lane&15, row=(lane>>4)*4+reg
  int isb = 1;
  if (MODE == 0) isb = *flagp;
#pragma unroll
  for (int i = 0; i < 4; ++i) {
#pragma unroll
    for (int j = 0; j < 4; ++j) {
      int n = n0 + wn + j * 16 + lc;
      float bv = 0.0f;
      if (MODE == 0) {
        if (isb) bv = b2f(((const u16*)bias)[n]);
        else     bv = ((const float*)bias)[n];
      }
#pragma unroll
      for (int r = 0; r < 4; ++r) {
        int m = m0 + wm + i * 16 + lq * 4 + r;
        float v = acc[i][j][r] * scal + bv;
        if (MODE == 0) {
          if (isb) ((u16*)C)[(long)m * N + n] = f2b(v);
          else     ((float*)C)[(long)m * N + n] = v;
        } else {
          int b = m >> 12, s = m & (S_LEN - 1);
          int h = n >> 6, dh = n & (DHEAD - 1);
          if (MODE == 1)
            ((u16*)C)[(((long)(b * NH + h)) * S_LEN + s) * DHEAD + dh] = f2b(v);
          else
            ((u16*)C)[(((long)(b * NH + h)) * DHEAD + dh) * S_LEN + s] = f2b(v);
        }
      }
    }
  }
}

// ---------------------------------------------------------------------------
// Flash attention v5 (causal), S^T formulation, 32 q per wave.
//   Q (pre-scaled by QSCALE), K: [B,H,S,DH]; Vt: [B,H,DH,S]; ctx: [B,S,H*DH]
// 1 block = (b, h, 128 q-rows), 4 waves x 32 q (two 16-q halves per wave;
// ak/av frag reads shared across halves). kv-tile = 64, staged in LDS with
// register prefetch. Main loop mask-free; only the 2 diagonal tiles mask.
// p = exp2(score') unnormalized (score' pre-scaled); one l-reduction at end.
// LDS = 27.6 KB -> 2 blocks/CU.
// ---------------------------------------------------------------------------
#define LDP 72  // padded row stride in u16 (144 B)

__global__ __launch_bounds__(256, 2)
void flash_attn(const u16* __restrict__ Q, const u16* __restrict__ K,
                const u16* __restrict__ Vt, u16* __restrict__ ctx) {
  __shared__ __align__(16) u16 lK[64 * LDP];     // [kv][dh]
  __shared__ __align__(16) u16 lV[64 * LDP];     // [dh][kv]
  __shared__ __align__(16) u16 lP[4][16 * LDP];  // per-wave P[q][kv] (reused per q-half)

  const int tid = threadIdx.x;
  const int w = tid >> 6;      // 0..3
  const int lane = tid & 63;
  const int lc = lane & 15;
  const int lq = lane >> 4;
  // reversed grid.x: longest (most k-tiles) blocks dispatch first
  const int q0 = (gridDim.x - 1 - (int)blockIdx.x) * 128;
  const int h = blockIdx.y;
  const int b = blockIdx.z;
  const int bh = b * NH + h;
  const u16* Qb = Q + (long)bh * S_LEN * DHEAD;
  const u16* Kb = K + (long)bh * S_LEN * DHEAD;
  const u16* Vb = Vt + (long)bh * DHEAD * S_LEN;

  const int qa = q0 + w * 32;  // wave's q base; lane handles q = qa+qh*16+lc

  // Q B-operand frags (loop-invariant, registers), per q-half
  bf16x8 aq[2][2];
#pragma unroll
  for (int qh = 0; qh < 2; ++qh)
#pragma unroll
    for (int t = 0; t < 2; ++t)
      aq[qh][t] = *(const bf16x8*)(Qb + (long)(qa + qh * 16 + lc) * DHEAD + t * 32 + lq * 8);

  // staging: 256 threads x 32B = 8192B = one 64x64 bf16 tile per buffer
  const int srow = tid >> 2;        // 0..63
  const int scol = (tid & 3) * 16;  // 0,16,32,48
  const u16* kp = Kb + (long)srow * DHEAD + scol;
  const u16* vp = Vb + (long)srow * S_LEN + scol;

  const int kmax = q0 + 64;  // last kv-tile base
  bf16x8 kr0 = *(const bf16x8*)kp;
  bf16x8 kr1 = *(const bf16x8*)(kp + 8);
  bf16x8 vr0 = *(const bf16x8*)vp;
  bf16x8 vr1 = *(const bf16x8*)(vp + 8);

  f32x4 o_acc[2][4] = {};
  float lsum[2] = {0.0f, 0.0f};

  for (int k0 = 0; k0 <= kmax; k0 += 64) {
    *(bf16x8*)&lK[srow * LDP + scol] = kr0;
    *(bf16x8*)&lK[srow * LDP + scol + 8] = kr1;
    *(bf16x8*)&lV[srow * LDP + scol] = vr0;
    *(bf16x8*)&lV[srow * LDP + scol + 8] = vr1;
    __syncthreads();  // stores visible to all waves

    if (k0 + 64 <= kmax) {  // prefetch next tile; retires at next iter's write
      kr0 = *(const bf16x8*)(kp + (long)(k0 + 64) * DHEAD);
      kr1 = *(const bf16x8*)(kp + (long)(k0 + 64) * DHEAD + 8);
      vr0 = *(const bf16x8*)(vp + k0 + 64);
      vr1 = *(const bf16x8*)(vp + k0 + 64 + 8);
    }

    // S^T: sc[qh][jm] holds (kv = k0+jm*16+lq*4+r, q = qa+qh*16+lc)
    f32x4 sc[2][4] = {};
#pragma unroll
    for (int jm = 0; jm < 4; ++jm) {
      bf16x8 ak0 = *(const bf16x8*)&lK[(jm * 16 + lc) * LDP + lq * 8];
      bf16x8 ak1 = *(const bf16x8*)&lK[(jm * 16 + lc) * LDP + 32 + lq * 8];
      sc[0][jm] = __builtin_amdgcn_mfma_f32_16x16x32_bf16(ak0, aq[0][0], sc[0][jm], 0, 0, 0);
      sc[0][jm] = __builtin_amdgcn_mfma_f32_16x16x32_bf16(ak1, aq[0][1], sc[0][jm], 0, 0, 0);
      sc[1][jm] = __builtin_amdgcn_mfma_f32_16x16x32_bf16(ak0, aq[1][0], sc[1][jm], 0, 0, 0);
      sc[1][jm] = __builtin_amdgcn_mfma_f32_16x16x32_bf16(ak1, aq[1][1], sc[1][jm], 0, 0, 0);
    }

    // softmax-lite: p = exp2(score'); mask only on the 2 diagonal tiles
    const bool masked = (k0 + 64 > q0);
    u32x2 pb[2][4];
#pragma unroll
    for (int qh = 0; qh < 2; ++qh) {
      const int myq = qa + qh * 16 + lc;
      float ls = 0.0f;
#pragma unroll
      for (int jm = 0; jm < 4; ++jm) {
        float e0 = exp2f(sc[qh][jm][0]);
        float e1 = exp2f(sc[qh][jm][1]);
        float e2 = exp2f(sc[qh][jm][2]);
        float e3 = exp2f(sc[qh][jm][3]);
        if (masked) {
          int kv = k0 + jm * 16 + lq * 4;
          e0 = (kv + 0 > myq) ? 0.0f : e0;
          e1 = (kv + 1 > myq) ? 0.0f : e1;
          e2 = (kv + 2 > myq) ? 0.0f : e2;
          e3 = (kv + 3 > myq) ? 0.0f : e3;
        }
        ls += (e0 + e1) + (e2 + e3);
        pb[qh][jm][0] = pk2(e1, e0);
        pb[qh][jm][1] = pk2(e3, e2);
      }
      lsum[qh] += ls;
    }

    // V A-operand frags (shared across q-halves)
    bf16x8 av[4][2];
#pragma unroll
    for (int jd = 0; jd < 4; ++jd) {
      av[jd][0] = *(const bf16x8*)&lV[(jd * 16 + lc) * LDP + lq * 8];
      av[jd][1] = *(const bf16x8*)&lV[(jd * 16 + lc) * LDP + 32 + lq * 8];
    }

    // O^T += V^T · P^T, per q-half through the wave-private lP buffer
#pragma unroll
    for (int qh = 0; qh < 2; ++qh) {
#pragma unroll
      for (int jm = 0; jm < 4; ++jm)
        *(u32x2*)&lP[w][lc * LDP + jm * 16 + lq * 4] = pb[qh][jm];
      // same-wave DS ordering: reads see the writes; next qh's writes wait
      bf16x8 bp0 = *(const bf16x8*)&lP[w][lc * LDP + lq * 8];
      bf16x8 bp1 = *(const bf16x8*)&lP[w][lc * LDP + 32 + lq * 8];
#pragma unroll
      for (int jd = 0; jd < 4; ++jd) {
        o_acc[qh][jd] = __builtin_amdgcn_mfma_f32_16x16x32_bf16(av[jd][0], bp0, o_acc[qh][jd], 0, 0, 0);
        o_acc[qh][jd] = __builtin_amdgcn_mfma_f32_16x16x32_bf16(av[jd][1], bp1, o_acc[qh][jd], 0, 0, 0);
      }
    }
    __syncthreads();  // all frag reads done before next iter's LDS overwrite
  }

  // final l reduction across the 4 quads sharing q, then store
#pragma unroll
  for (int qh = 0; qh < 2; ++qh) {
    float ls = lsum[qh];
    ls += __shfl_xor(ls, 16, 64);
    ls += __shfl_xor(ls, 32, 64);
    float inv = 1.0f / ls;
    const int myq = qa + qh * 16 + lc;
    u16* cp = ctx + ((long)(b * S_LEN + myq)) * DMODEL + h * DHEAD;
#pragma unroll
    for (int jd = 0; jd < 4; ++jd) {
      u16x4 ov;
#pragma unroll
      for (int r = 0; r < 4; ++r) ov[r] = f2b(o_acc[qh][jd][r] * inv);
      *(u16x4*)&cp[jd * 16 + lq * 4] = ov;
    }
  }
}

// ---------------------------------------------------------------------------
// ws layout (u16 elems): wt[4M] | Q[8M] | Vt[8M] | xc-then-ctx[8M] | flag
//   = 56 MB + 4 B.   K rides in d_out until the final GEMM overwrites it.
// ---------------------------------------------------------------------------
extern "C" void kernel_launch(void* const* d_in, const int* in_sizes, int n_in,
                              void* d_out, int out_size, void* d_ws, size_t ws_size,
                              hipStream_t stream) {
  const void* x  = d_in[0];
  const void* Wq = d_in[1];
  const void* Wk = d_in[2];
  const void* Wv = d_in[3];
  const void* Wo = d_in[4];
  const void* bo = d_in[5];
  u16* ws = (u16*)d_ws;

  u16* wt  = ws;                        // 4 * 1,048,576
  u16* wtq = wt;
  u16* wtk = wt + 1048576;
  u16* wtv = wt + 2097152;
  u16* wto = wt + 3145728;
  u16* Qb  = ws + 4194304;              // 8,388,608
  u16* Vtb = ws + 12582912;             // 8,388,608
  u16* xc  = ws + 20971520;             // 8,388,608 (reused as ctx after QKV)
  u16* ctx = xc;
  int* flag = (int*)(ws + 29360128);
  u16* Kb  = (u16*)d_out;               // bf16 K scratch in d_out (16 MB)

  detect_dtype<<<1, 256, 0, stream>>>((const unsigned int*)x, flag);
  convert_x<<<8192, 256, 0, stream>>>(x, xc, flag);
  transpose4<<<dim3(32, 32, 4), dim3(32, 8), 0, stream>>>(Wq, Wk, Wv, Wo, wt, flag);

  dim3 g(DMODEL / BN, MTOK / BM), blk(256);
  gemm_bt<1><<<g, blk, 0, stream>>>(xc, wtq, nullptr, Qb,  MTOK, DMODEL, DMODEL, flag, QSCALE);
  gemm_bt<1><<<g, blk, 0, stream>>>(xc, wtk, nullptr, Kb,  MTOK, DMODEL, DMODEL, flag, 1.0f);
  gemm_bt<2><<<g, blk, 0, stream>>>(xc, wtv, nullptr, Vtb, MTOK, DMODEL, DMODEL, flag, 1.0f);

  flash_attn<<<dim3(S_LEN / 128, NH, BATCH), 256, 0, stream>>>(Qb, Kb, Vtb, ctx);

  gemm_bt<0><<<g, blk, 0, stream>>>(ctx, wto, bo, d_out, MTOK, DMODEL, DMODEL, flag, 1.0f);
}

// Round 9
// 435.470 us; speedup vs baseline: 1.0267x; 1.0267x over previous
//
#include <hip/hip_runtime.h>
#include <hip/hip_bf16.h>
#include <stdint.h>
#include <math.h>

// Problem constants (fixed by the reference)
#define BATCH 2
#define S_LEN 4096
#define DMODEL 1024
#define NH 16
#define DHEAD 64
#define MTOK (BATCH * S_LEN)  // 8192

// exp(score/8) == exp2(score * 0.125*log2(e)); folded into Q-projection epilogue.
#define QSCALE 0.1803368801111793f

typedef unsigned short u16;
typedef __attribute__((ext_vector_type(8))) short bf16x8;  // 8 bf16 = 4 VGPRs
typedef __attribute__((ext_vector_type(4))) float f32x4;
typedef __attribute__((ext_vector_type(4))) unsigned short u16x4;

__device__ __forceinline__ float b2f(u16 u) {
  union { unsigned int i; float f; } v; v.i = ((unsigned int)u) << 16; return v.f;
}
__device__ __forceinline__ u16 f2b(float f) {
  union { float f; unsigned int i; } v; v.f = f;
  unsigned int r = v.i + 0x7FFF + ((v.i >> 16) & 1);  // RNE
  return (u16)(r >> 16);
}
// pack two f32 into (bf16_trunc(hi)<<16)|bf16_trunc(lo) with one v_perm_b32
__device__ __forceinline__ unsigned int pk2(float hi, float lo) {
  union { float f; unsigned int u; } a, b; a.f = hi; b.f = lo;
  return __builtin_amdgcn_perm(a.u, b.u, 0x07060302u);
}

// async global->LDS, 16B per lane; LDS dest is wave-uniform base (HW adds lane*16).
__device__ __forceinline__ void gl_lds16(const u16* g, u16* l) {
  __builtin_amdgcn_global_load_lds(
      (__attribute__((address_space(1))) void*)(u16*)g,
      (__attribute__((address_space(3))) void*)l, 16, 0, 0);
}

// ---------------------------------------------------------------------------
// Input dtype detection (bf16 vs f32 buffers) — statistical, see round 4.
// flag = 1 -> bf16; flag = 0 -> f32.
// ---------------------------------------------------------------------------
__global__ void detect_dtype(const unsigned int* __restrict__ x, int* __restrict__ flag) {
  __shared__ int cnt;
  if (threadIdx.x == 0) cnt = 0;
  __syncthreads();
  int c = 0;
  for (int i = threadIdx.x; i < 4096; i += 256) {
    unsigned int w = x[i];
    int e = (w >> 7) & 0xFF;  // bf16 exponent field of the low u16
    if (e >= 100 && e <= 135) c++;
  }
  atomicAdd(&cnt, c);
  __syncthreads();
  if (threadIdx.x == 0) *flag = (cnt > 2048) ? 1 : 0;
}

// ---------------------------------------------------------------------------
// Canonicalize x -> bf16. 8192 blocks x 256 threads x 4 elems = 8,388,608.
// ---------------------------------------------------------------------------
__global__ void convert_x(const void* __restrict__ xin, u16* __restrict__ xc,
                          const int* __restrict__ flagp) {
  const int isb = *flagp;
  long e = ((long)blockIdx.x * 256 + threadIdx.x) * 4;
  if (isb) {
    *(uint2*)&xc[e] = *(const uint2*)((const u16*)xin + e);  // 8B copy
  } else {
    float4 f = *(const float4*)((const float*)xin + e);
    xc[e + 0] = f2b(f.x);
    xc[e + 1] = f2b(f.y);
    xc[e + 2] = f2b(f.z);
    xc[e + 3] = f2b(f.w);
  }
}

// ---------------------------------------------------------------------------
// Weight transpose + dtype conversion: out[n*1024+k] = bf16(W[k*1024+n])
// ---------------------------------------------------------------------------
__global__ void transpose4(const void* __restrict__ W0, const void* __restrict__ W1,
                           const void* __restrict__ W2, const void* __restrict__ W3,
                           u16* __restrict__ out, const int* __restrict__ flagp) {
  __shared__ u16 tile[32][33];
  const int isb = *flagp;
  int z = blockIdx.z;
  const void* W = (z == 0) ? W0 : (z == 1) ? W1 : (z == 2) ? W2 : W3;
  u16* o = out + (long)z * (DMODEL * DMODEL);
  int x = blockIdx.x * 32 + threadIdx.x;
  int y0 = blockIdx.y * 32;
  if (isb) {
    const u16* Wb = (const u16*)W;
#pragma unroll
    for (int i = 0; i < 32; i += 8)
      tile[threadIdx.y + i][threadIdx.x] = Wb[(long)(y0 + threadIdx.y + i) * DMODEL + x];
  } else {
    const float* Wf = (const float*)W;
#pragma unroll
    for (int i = 0; i < 32; i += 8)
      tile[threadIdx.y + i][threadIdx.x] = f2b(Wf[(long)(y0 + threadIdx.y + i) * DMODEL + x]);
  }
  __syncthreads();
  int x2 = blockIdx.y * 32 + threadIdx.x;
  int y2 = blockIdx.x * 32;
#pragma unroll
  for (int i = 0; i < 32; i += 8)
    o[(long)(y2 + threadIdx.y + i) * DMODEL + x2] = tile[threadIdx.x][threadIdx.y + i];
}

// ---------------------------------------------------------------------------
// C = scal * (A[M,K] @ Bt[N,K]^T)  (m97: 128x128, BK=32, global_load_lds x16)
// MODE 0: out  (dtype per flag), + bias (dtype per flag)
// MODE 1: scatter bf16 to [B,H,S,DH]   (Q and K; Q gets scal=QSCALE)
// MODE 2: scatter bf16 to [B,H,DH,S]   (V transposed)
// ---------------------------------------------------------------------------
#define BM 128
#define BN 128
#define BK 32

template <int MODE>
__global__ __launch_bounds__(256)
void gemm_bt(const u16* __restrict__ A, const u16* __restrict__ Bt,
             const void* __restrict__ bias, void* __restrict__ C,
             int M, int N, int Kd, const int* __restrict__ flagp, float scal) {
  __shared__ __align__(16) u16 lA[BM * BK];
  __shared__ __align__(16) u16 lB[BN * BK];
  const int tid = threadIdx.x;
  const int w = tid >> 6;
  const int lane = tid & 63;
  const int m0 = blockIdx.y * BM;
  const int n0 = blockIdx.x * BN;
  const int wm = (w >> 1) * 64;
  const int wn = (w & 1) * 64;
  const int lc = lane & 15;
  const int lq = lane >> 4;

  f32x4 acc[4][4] = {};

  for (int k0 = 0; k0 < Kd; k0 += BK) {
    __syncthreads();  // previous tile fully consumed
#pragma unroll
    for (int jj = 0; jj < 2; ++jj) {
      int base = (jj * 4 + w) * 512;  // wave-uniform LDS base (u16 elems)
      int e = base + lane * 8;        // this lane's element (16B per lane)
      int row = e >> 5, col = e & 31;
      gl_lds16(A + (long)(m0 + row) * Kd + k0 + col, lA + base);
      gl_lds16(Bt + (long)(n0 + row) * Kd + k0 + col, lB + base);
    }
    __syncthreads();  // drains vmcnt before consumption

    bf16x8 af[4], bg[4];
#pragma unroll
    for (int i = 0; i < 4; ++i)
      af[i] = *(const bf16x8*)&lA[(wm + i * 16 + lc) * BK + lq * 8];
#pragma unroll
    for (int j = 0; j < 4; ++j)
      bg[j] = *(const bf16x8*)&lB[(wn + j * 16 + lc) * BK + lq * 8];
#pragma unroll
    for (int i = 0; i < 4; ++i)
#pragma unroll
      for (int j = 0; j < 4; ++j)
        acc[i][j] = __builtin_amdgcn_mfma_f32_16x16x32_bf16(af[i], bg[j], acc[i][j], 0, 0, 0);
  }

  // Epilogue: C/D layout col=lane&15, row=(lane>>4)*4+reg
  int isb = 1;
  if (MODE == 0) isb = *flagp;
#pragma unroll
  for (int i = 0; i < 4; ++i) {
#pragma unroll
    for (int j = 0; j < 4; ++j) {
      int n = n0 + wn + j * 16 + lc;
      float bv = 0.0f;
      if (MODE == 0) {
        if (isb) bv = b2f(((const u16*)bias)[n]);
        else     bv = ((const float*)bias)[n];
      }
#pragma unroll
      for (int r = 0; r < 4; ++r) {
        int m = m0 + wm + i * 16 + lq * 4 + r;
        float v = acc[i][j][r] * scal + bv;
        if (MODE == 0) {
          if (isb) ((u16*)C)[(long)m * N + n] = f2b(v);
          else     ((float*)C)[(long)m * N + n] = v;
        } else {
          int b = m >> 12, s = m & (S_LEN - 1);
          int h = n >> 6, dh = n & (DHEAD - 1);
          if (MODE == 1)
            ((u16*)C)[(((long)(b * NH + h)) * S_LEN + s) * DHEAD + dh] = f2b(v);
          else
            ((u16*)C)[(((long)(b * NH + h)) * DHEAD + dh) * S_LEN + s] = f2b(v);
        }
      }
    }
  }
}

// ---------------------------------------------------------------------------
// Flash attention v6 (causal), S^T form, 512 thr / 8 waves / 16 q per wave.
//   Q (pre-scaled), K: [B,H,S,DH]; Vt: [B,H,DH,S]; ctx: [B,S,H*DH]
// LDS diet for 2 blocks/CU (16 waves/CU):
//   lK/lV: 64x64 tiles, NO padding, 16B XOR swizzle (chunk ^= row&7) -> 8192 B
//          each; staging writes and b128 frag reads both 2-way (free).
//   lP: wave-private 16q x 32kv half-buffer, stride 40 u16 -> 10240 B total.
//   Total 26624 B  (2 x 27648 proven co-resident in r5).
// Wave-uniform skip of fully-masked tiles; register prefetch; exp2 softmax.
// ---------------------------------------------------------------------------
__global__ __launch_bounds__(512, 4)
void flash_attn(const u16* __restrict__ Q, const u16* __restrict__ K,
                const u16* __restrict__ Vt, u16* __restrict__ ctx) {
  __shared__ __align__(16) u16 lK[64 * 64];      // swizzled [kv][dh]
  __shared__ __align__(16) u16 lV[64 * 64];      // swizzled [dh][kv]
  __shared__ __align__(16) u16 lP[8 * 16 * 40];  // per-wave P[q][kv'] halves

  const int tid = threadIdx.x;
  const int w = tid >> 6;      // 0..7
  const int lane = tid & 63;
  const int lc = lane & 15;
  const int lq = lane >> 4;
  // reversed grid.x: longest (most k-tiles) blocks dispatch first
  const int q0 = (gridDim.x - 1 - (int)blockIdx.x) * 128;
  const int h = blockIdx.y;
  const int b = blockIdx.z;
  const int bh = b * NH + h;
  const u16* Qb = Q + (long)bh * S_LEN * DHEAD;
  const u16* Kb = K + (long)bh * S_LEN * DHEAD;
  const u16* Vb = Vt + (long)bh * DHEAD * S_LEN;

  const int qa = q0 + w * 16;   // wave's q base
  const int myq = qa + lc;      // this lane's q column

  // Q B-operand frags (loop-invariant, registers)
  bf16x8 aq[2];
#pragma unroll
  for (int t = 0; t < 2; ++t)
    aq[t] = *(const bf16x8*)(Qb + (long)myq * DHEAD + t * 32 + lq * 8);

  // staging: 512 thr x 16B per buffer = one 64x64 bf16 tile each
  const int srow = tid >> 3;                    // 0..63
  const int sch = tid & 7;                      // 16B chunk 0..7
  const int sdst = srow * 64 + ((sch ^ (srow & 7)) * 8);  // swizzled u16 addr
  const u16* kp = Kb + (long)srow * DHEAD + sch * 8;
  const u16* vp = Vb + (long)srow * S_LEN + sch * 8;

  const int kmax = q0 + 64;  // last kv-tile base (covers q up to q0+127)
  bf16x8 kr = *(const bf16x8*)kp;
  bf16x8 vr = *(const bf16x8*)vp;

  u16* myP = &lP[w * 640];  // 16 x 40 u16, wave-private

  f32x4 o_acc[4] = {};
  float lsum = 0.0f;
  const int xsw = (lc & 7);  // read-side swizzle key (row&7 == lc&7)

  for (int k0 = 0; k0 <= kmax; k0 += 64) {
    *(bf16x8*)&lK[sdst] = kr;
    *(bf16x8*)&lV[sdst] = vr;
    __syncthreads();  // stores visible to all waves

    if (k0 + 64 <= kmax) {  // prefetch next tile; retires at next iter's write
      kr = *(const bf16x8*)(kp + (long)(k0 + 64) * DHEAD);
      vr = *(const bf16x8*)(vp + k0 + 64);
    }

    if (k0 <= qa + 15) {  // wave-uniform: skip fully-masked tiles
      // S^T: sc[jm] holds (kv = k0+jm*16+lq*4+r, q = myq)
      f32x4 sc[4] = {};
#pragma unroll
      for (int jm = 0; jm < 4; ++jm) {
        const int rk = (jm * 16 + lc) * 64;
        bf16x8 ak0 = *(const bf16x8*)&lK[rk + ((lq ^ xsw) * 8)];
        bf16x8 ak1 = *(const bf16x8*)&lK[rk + (((4 + lq) ^ xsw) * 8)];
        sc[jm] = __builtin_amdgcn_mfma_f32_16x16x32_bf16(ak0, aq[0], sc[jm], 0, 0, 0);
        sc[jm] = __builtin_amdgcn_mfma_f32_16x16x32_bf16(ak1, aq[1], sc[jm], 0, 0, 0);
      }

      // softmax-lite: p = exp2(score'); mask only near the diagonal
      const bool masked = (k0 + 63 > qa);
      unsigned int pb[4][2];
      float ls = 0.0f;
#pragma unroll
      for (int jm = 0; jm < 4; ++jm) {
        float e0 = exp2f(sc[jm][0]);
        float e1 = exp2f(sc[jm][1]);
        float e2 = exp2f(sc[jm][2]);
        float e3 = exp2f(sc[jm][3]);
        if (masked) {
          int kv = k0 + jm * 16 + lq * 4;
          e0 = (kv + 0 > myq) ? 0.0f : e0;
          e1 = (kv + 1 > myq) ? 0.0f : e1;
          e2 = (kv + 2 > myq) ? 0.0f : e2;
          e3 = (kv + 3 > myq) ? 0.0f : e3;
        }
        ls += (e0 + e1) + (e2 + e3);
        pb[jm][0] = pk2(e1, e0);
        pb[jm][1] = pk2(e3, e2);
      }
      lsum += ls;

      // V A-operand frags
      bf16x8 av[4][2];
#pragma unroll
      for (int jd = 0; jd < 4; ++jd) {
        const int rv = (jd * 16 + lc) * 64;
        av[jd][0] = *(const bf16x8*)&lV[rv + ((lq ^ xsw) * 8)];
        av[jd][1] = *(const bf16x8*)&lV[rv + (((4 + lq) ^ xsw) * 8)];
      }

      // O^T += V^T · P^T in two 32-kv halves through the wave-private lP
#pragma unroll
      for (int hh = 0; hh < 2; ++hh) {
        *(uint2*)&myP[lc * 40 + lq * 4] =
            make_uint2(pb[hh * 2][0], pb[hh * 2][1]) /*placeholder*/;
        // NOTE: the two u32 of pb[jm] are kv (lq*4..+3); rows jm'=0,1 below
        *(uint2*)&myP[lc * 40 + 16 + lq * 4] =
            make_uint2(pb[hh * 2 + 1][0], pb[hh * 2 + 1][1]);
        // fix first write (jm'=0) with correct pair:
        *(uint2*)&myP[lc * 40 + lq * 4] =
            make_uint2(pb[hh * 2][0], pb[hh * 2][1]);
        bf16x8 bp = *(const bf16x8*)&myP[lc * 40 + lq * 8];
#pragma unroll
        for (int jd = 0; jd < 4; ++jd)
          o_acc[jd] = __builtin_amdgcn_mfma_f32_16x16x32_bf16(av[jd][hh], bp, o_acc[jd], 0, 0, 0);
      }
    }
    __syncthreads();  // all frag reads done before next iter's LDS overwrite
  }

  // final l reduction across the 4 quads sharing q=lc
  lsum += __shfl_xor(lsum, 16, 64);
  lsum += __shfl_xor(lsum, 32, 64);
  float inv = 1.0f / lsum;

  // epilogue: ctx[b, q=myq, h*64 + dh], dh = jd*16 + lq*4 + r  (8B stores)
  u16* cp = ctx + ((long)(b * S_LEN + myq)) * DMODEL + h * DHEAD;
#pragma unroll
  for (int jd = 0; jd < 4; ++jd) {
    u16x4 ov;
#pragma unroll
    for (int r = 0; r < 4; ++r) ov[r] = f2b(o_acc[jd][r] * inv);
    *(u16x4*)&cp[jd * 16 + lq * 4] = ov;
  }
}

// ---------------------------------------------------------------------------
// ws layout (u16 elems): wt[4M] | Q[8M] | Vt[8M] | xc-then-ctx[8M] | flag
//   = 56 MB + 4 B.   K rides in d_out until the final GEMM overwrites it.
// ---------------------------------------------------------------------------
extern "C" void kernel_launch(void* const* d_in, const int* in_sizes, int n_in,
                              void* d_out, int out_size, void* d_ws, size_t ws_size,
                              hipStream_t stream) {
  const void* x  = d_in[0];
  const void* Wq = d_in[1];
  const void* Wk = d_in[2];
  const void* Wv = d_in[3];
  const void* Wo = d_in[4];
  const void* bo = d_in[5];
  u16* ws = (u16*)d_ws;

  u16* wt  = ws;                        // 4 * 1,048,576
  u16* wtq = wt;
  u16* wtk = wt + 1048576;
  u16* wtv = wt + 2097152;
  u16* wto = wt + 3145728;
  u16* Qb  = ws + 4194304;              // 8,388,608
  u16* Vtb = ws + 12582912;             // 8,388,608
  u16* xc  = ws + 20971520;             // 8,388,608 (reused as ctx after QKV)
  u16* ctx = xc;
  int* flag = (int*)(ws + 29360128);
  u16* Kb  = (u16*)d_out;               // bf16 K scratch in d_out (16 MB)

  detect_dtype<<<1, 256, 0, stream>>>((const unsigned int*)x, flag);
  convert_x<<<8192, 256, 0, stream>>>(x, xc, flag);
  transpose4<<<dim3(32, 32, 4), dim3(32, 8), 0, stream>>>(Wq, Wk, Wv, Wo, wt, flag);

  dim3 g(DMODEL / BN, MTOK / BM), blk(256);
  gemm_bt<1><<<g, blk, 0, stream>>>(xc, wtq, nullptr, Qb,  MTOK, DMODEL, DMODEL, flag, QSCALE);
  gemm_bt<1><<<g, blk, 0, stream>>>(xc, wtk, nullptr, Kb,  MTOK, DMODEL, DMODEL, flag, 1.0f);
  gemm_bt<2><<<g, blk, 0, stream>>>(xc, wtv, nullptr, Vtb, MTOK, DMODEL, DMODEL, flag, 1.0f);

  flash_attn<<<dim3(S_LEN / 128, NH, BATCH), 512, 0, stream>>>(Qb, Kb, Vtb, ctx);

  gemm_bt<0><<<g, blk, 0, stream>>>(ctx, wto, bo, d_out, MTOK, DMODEL, DMODEL, flag, 1.0f);
}

// Round 10
// 411.316 us; speedup vs baseline: 1.0870x; 1.0587x over previous
//
#include <hip/hip_runtime.h>
#include <hip/hip_bf16.h>
#include <stdint.h>
#include <math.h>

// Problem constants (fixed by the reference)
#define BATCH 2
#define S_LEN 4096
#define DMODEL 1024
#define NH 16
#define DHEAD 64
#define MTOK (BATCH * S_LEN)  // 8192

// exp(score/8) == exp2(score * 0.125*log2(e)); folded into Q-projection epilogue.
#define QSCALE 0.1803368801111793f

typedef unsigned short u16;
typedef __attribute__((ext_vector_type(8))) short bf16x8;  // 8 bf16 = 4 VGPRs
typedef __attribute__((ext_vector_type(4))) float f32x4;
typedef __attribute__((ext_vector_type(4))) unsigned short u16x4;

__device__ __forceinline__ float b2f(u16 u) {
  union { unsigned int i; float f; } v; v.i = ((unsigned int)u) << 16; return v.f;
}
__device__ __forceinline__ u16 f2b(float f) {
  union { float f; unsigned int i; } v; v.f = f;
  unsigned int r = v.i + 0x7FFF + ((v.i >> 16) & 1);  // RNE
  return (u16)(r >> 16);
}
// pack two f32 into (bf16_trunc(hi)<<16)|bf16_trunc(lo) with one v_perm_b32
__device__ __forceinline__ unsigned int pk2(float hi, float lo) {
  union { float f; unsigned int u; } a, b; a.f = hi; b.f = lo;
  return __builtin_amdgcn_perm(a.u, b.u, 0x07060302u);
}

// async global->LDS, 16B per lane; LDS dest is wave-uniform base (HW adds lane*16).
__device__ __forceinline__ void gl_lds16(const u16* g, u16* l) {
  __builtin_amdgcn_global_load_lds(
      (__attribute__((address_space(1))) void*)(u16*)g,
      (__attribute__((address_space(3))) void*)l, 16, 0, 0);
}

// ---------------------------------------------------------------------------
// Input dtype detection (bf16 vs f32 buffers) — statistical, see round 4.
// flag = 1 -> bf16; flag = 0 -> f32.
// ---------------------------------------------------------------------------
__global__ void detect_dtype(const unsigned int* __restrict__ x, int* __restrict__ flag) {
  __shared__ int cnt;
  if (threadIdx.x == 0) cnt = 0;
  __syncthreads();
  int c = 0;
  for (int i = threadIdx.x; i < 4096; i += 256) {
    unsigned int w = x[i];
    int e = (w >> 7) & 0xFF;  // bf16 exponent field of the low u16
    if (e >= 100 && e <= 135) c++;
  }
  atomicAdd(&cnt, c);
  __syncthreads();
  if (threadIdx.x == 0) *flag = (cnt > 2048) ? 1 : 0;
}

// ---------------------------------------------------------------------------
// Canonicalize x -> bf16. 8192 blocks x 256 threads x 4 elems = 8,388,608.
// ---------------------------------------------------------------------------
__global__ void convert_x(const void* __restrict__ xin, u16* __restrict__ xc,
                          const int* __restrict__ flagp) {
  const int isb = *flagp;
  long e = ((long)blockIdx.x * 256 + threadIdx.x) * 4;
  if (isb) {
    *(uint2*)&xc[e] = *(const uint2*)((const u16*)xin + e);  // 8B copy
  } else {
    float4 f = *(const float4*)((const float*)xin + e);
    xc[e + 0] = f2b(f.x);
    xc[e + 1] = f2b(f.y);
    xc[e + 2] = f2b(f.z);
    xc[e + 3] = f2b(f.w);
  }
}

// ---------------------------------------------------------------------------
// Weight transpose + dtype conversion: out[n*1024+k] = bf16(W[k*1024+n])
// ---------------------------------------------------------------------------
__global__ void transpose4(const void* __restrict__ W0, const void* __restrict__ W1,
                           const void* __restrict__ W2, const void* __restrict__ W3,
                           u16* __restrict__ out, const int* __restrict__ flagp) {
  __shared__ u16 tile[32][33];
  const int isb = *flagp;
  int z = blockIdx.z;
  const void* W = (z == 0) ? W0 : (z == 1) ? W1 : (z == 2) ? W2 : W3;
  u16* o = out + (long)z * (DMODEL * DMODEL);
  int x = blockIdx.x * 32 + threadIdx.x;
  int y0 = blockIdx.y * 32;
  if (isb) {
    const u16* Wb = (const u16*)W;
#pragma unroll
    for (int i = 0; i < 32; i += 8)
      tile[threadIdx.y + i][threadIdx.x] = Wb[(long)(y0 + threadIdx.y + i) * DMODEL + x];
  } else {
    const float* Wf = (const float*)W;
#pragma unroll
    for (int i = 0; i < 32; i += 8)
      tile[threadIdx.y + i][threadIdx.x] = f2b(Wf[(long)(y0 + threadIdx.y + i) * DMODEL + x]);
  }
  __syncthreads();
  int x2 = blockIdx.y * 32 + threadIdx.x;
  int y2 = blockIdx.x * 32;
#pragma unroll
  for (int i = 0; i < 32; i += 8)
    o[(long)(y2 + threadIdx.y + i) * DMODEL + x2] = tile[threadIdx.x][threadIdx.y + i];
}

// ---------------------------------------------------------------------------
// Shared GEMM core: 128x128 tile, BK=32, global_load_lds x16 staging.
// acc[i][j][r] computed for C-tile (m0,n0); epilogue differs per kernel.
// ---------------------------------------------------------------------------
#define BM 128
#define BN 128
#define BK 32

#define GEMM_CORE(A_, Bt_, Kd_)                                                   \
  __shared__ __align__(16) u16 lA[BM * BK];                                       \
  __shared__ __align__(16) u16 lB[BN * BK];                                       \
  const int tid = threadIdx.x;                                                    \
  const int w = tid >> 6;                                                         \
  const int lane = tid & 63;                                                      \
  const int m0 = blockIdx.y * BM;                                                 \
  const int n0 = blockIdx.x * BN;                                                 \
  const int wm = (w >> 1) * 64;                                                   \
  const int wn = (w & 1) * 64;                                                    \
  const int lc = lane & 15;                                                       \
  const int lq = lane >> 4;                                                       \
  f32x4 acc[4][4] = {};                                                           \
  for (int k0 = 0; k0 < (Kd_); k0 += BK) {                                        \
    __syncthreads();                                                              \
    _Pragma("unroll")                                                             \
    for (int jj = 0; jj < 2; ++jj) {                                              \
      int base = (jj * 4 + w) * 512;                                              \
      int e = base + lane * 8;                                                    \
      int row = e >> 5, col = e & 31;                                             \
      gl_lds16((A_) + (long)(m0 + row) * (Kd_) + k0 + col, lA + base);            \
      gl_lds16((Bt_) + (long)(n0 + row) * (Kd_) + k0 + col, lB + base);           \
    }                                                                             \
    __syncthreads();                                                              \
    bf16x8 af[4], bg[4];                                                          \
    _Pragma("unroll")                                                             \
    for (int i = 0; i < 4; ++i)                                                   \
      af[i] = *(const bf16x8*)&lA[(wm + i * 16 + lc) * BK + lq * 8];              \
    _Pragma("unroll")                                                             \
    for (int j = 0; j < 4; ++j)                                                   \
      bg[j] = *(const bf16x8*)&lB[(wn + j * 16 + lc) * BK + lq * 8];              \
    _Pragma("unroll")                                                             \
    for (int i = 0; i < 4; ++i)                                                   \
      _Pragma("unroll")                                                           \
      for (int j = 0; j < 4; ++j)                                                 \
        acc[i][j] = __builtin_amdgcn_mfma_f32_16x16x32_bf16(af[i], bg[j], acc[i][j], 0, 0, 0); \
  }

// ---------------------------------------------------------------------------
// Fused QKV projection: A = xc [8192,1024], Bt = wtq|wtk|wtv [3072,1024].
// n<1024 -> Q (scaled QSCALE) [B,H,S,DH]; n<2048 -> K [B,H,S,DH];
// else -> Vt [B,H,DH,S].
// ---------------------------------------------------------------------------
__global__ __launch_bounds__(256)
void gemm_qkv(const u16* __restrict__ A, const u16* __restrict__ Bt,
              u16* __restrict__ Qo, u16* __restrict__ Ko, u16* __restrict__ Vo) {
  GEMM_CORE(A, Bt, DMODEL)
#pragma unroll
  for (int i = 0; i < 4; ++i) {
#pragma unroll
    for (int j = 0; j < 4; ++j) {
      int n = n0 + wn + j * 16 + lc;
      int rgn = n >> 10;            // 0=Q 1=K 2=V
      int nn = n & 1023;
      int h = nn >> 6, dh = nn & (DHEAD - 1);
      float sc = (rgn == 0) ? QSCALE : 1.0f;
#pragma unroll
      for (int r = 0; r < 4; ++r) {
        int m = m0 + wm + i * 16 + lq * 4 + r;
        int b = m >> 12, s = m & (S_LEN - 1);
        float v = acc[i][j][r] * sc;
        long idx_r = (((long)(b * NH + h)) * S_LEN + s) * DHEAD + dh;   // Q/K
        long idx_v = (((long)(b * NH + h)) * DHEAD + dh) * S_LEN + s;   // Vt
        if (rgn == 0)      Qo[idx_r] = f2b(v);
        else if (rgn == 1) Ko[idx_r] = f2b(v);
        else               Vo[idx_v] = f2b(v);
      }
    }
  }
}

// ---------------------------------------------------------------------------
// Output projection: C[M,N] = A @ Bt^T + bias, dtype of out/bias per flag.
// ---------------------------------------------------------------------------
__global__ __launch_bounds__(256)
void gemm_out(const u16* __restrict__ A, const u16* __restrict__ Bt,
              const void* __restrict__ bias, void* __restrict__ C,
              const int* __restrict__ flagp) {
  GEMM_CORE(A, Bt, DMODEL)
  const int isb = *flagp;
#pragma unroll
  for (int i = 0; i < 4; ++i) {
#pragma unroll
    for (int j = 0; j < 4; ++j) {
      int n = n0 + wn + j * 16 + lc;
      float bv = isb ? b2f(((const u16*)bias)[n]) : ((const float*)bias)[n];
#pragma unroll
      for (int r = 0; r < 4; ++r) {
        int m = m0 + wm + i * 16 + lq * 4 + r;
        float v = acc[i][j][r] + bv;
        if (isb) ((u16*)C)[(long)m * DMODEL + n] = f2b(v);
        else     ((float*)C)[(long)m * DMODEL + n] = v;
      }
    }
  }
}

// ---------------------------------------------------------------------------
// Flash attention v7 (causal), S^T form, 256 thr / 4 waves / 16 q per wave.
//   Q (pre-scaled), K: [B,H,S,DH]; Vt: [B,H,DH,S]; ctx: [B,S,H*DH]
// 256-thread blocks co-reside (r5 evidence; 512-thr blocks never did —
// r7/r9). LDS 21504 B -> 3 blocks/CU under a 64 KiB budget = 12 waves/CU,
// 3 independent barrier groups.
//   lK/lV: 64x64, unpadded, 16B XOR swizzle (chunk ^= row&7) -> 8192 B each.
//   lP: wave-private 16q x 32kv halves, stride 40 u16 -> 5120 B.
// Wave-uniform fully-masked-tile skip; register prefetch; exp2 softmax-lite.
// ---------------------------------------------------------------------------
__global__ __launch_bounds__(256, 2)
void flash_attn(const u16* __restrict__ Q, const u16* __restrict__ K,
                const u16* __restrict__ Vt, u16* __restrict__ ctx) {
  __shared__ __align__(16) u16 lK[64 * 64];      // swizzled [kv][dh]
  __shared__ __align__(16) u16 lV[64 * 64];      // swizzled [dh][kv]
  __shared__ __align__(16) u16 lP[4 * 16 * 40];  // per-wave P halves

  const int tid = threadIdx.x;
  const int w = tid >> 6;      // 0..3
  const int lane = tid & 63;
  const int lc = lane & 15;
  const int lq = lane >> 4;
  // reversed grid.x: longest (most k-tiles) blocks dispatch first
  const int q0 = (gridDim.x - 1 - (int)blockIdx.x) * 64;
  const int h = blockIdx.y;
  const int b = blockIdx.z;
  const int bh = b * NH + h;
  const u16* Qb = Q + (long)bh * S_LEN * DHEAD;
  const u16* Kb = K + (long)bh * S_LEN * DHEAD;
  const u16* Vb = Vt + (long)bh * DHEAD * S_LEN;

  const int qa = q0 + w * 16;   // wave's q base
  const int myq = qa + lc;      // this lane's q column

  // Q B-operand frags (loop-invariant, registers)
  bf16x8 aq[2];
#pragma unroll
  for (int t = 0; t < 2; ++t)
    aq[t] = *(const bf16x8*)(Qb + (long)myq * DHEAD + t * 32 + lq * 8);

  // staging: 256 thr x 2 x 16B per buffer = one 64x64 bf16 tile each
  const int srow = tid >> 2;         // 0..63
  const int sc0 = (tid & 3) * 2;     // chunks sc0, sc0+1
  const int sd0 = srow * 64 + ((sc0 ^ (srow & 7)) * 8);
  const int sd1 = srow * 64 + (((sc0 + 1) ^ (srow & 7)) * 8);
  const u16* kp = Kb + (long)srow * DHEAD + sc0 * 8;
  const u16* vp = Vb + (long)srow * S_LEN + sc0 * 8;

  const int kmax = q0;  // last kv-tile base (q-tile = 64)
  bf16x8 kr0 = *(const bf16x8*)kp;
  bf16x8 kr1 = *(const bf16x8*)(kp + 8);
  bf16x8 vr0 = *(const bf16x8*)vp;
  bf16x8 vr1 = *(const bf16x8*)(vp + 8);

  u16* myP = &lP[w * 640];  // 16 x 40 u16, wave-private

  f32x4 o_acc[4] = {};
  float lsum = 0.0f;
  const int xsw = (lc & 7);  // read-side swizzle key (row&7 == lc&7)

  for (int k0 = 0; k0 <= kmax; k0 += 64) {
    *(bf16x8*)&lK[sd0] = kr0;
    *(bf16x8*)&lK[sd1] = kr1;
    *(bf16x8*)&lV[sd0] = vr0;
    *(bf16x8*)&lV[sd1] = vr1;
    __syncthreads();  // stores visible to all waves

    if (k0 + 64 <= kmax) {  // prefetch next tile; retires at next iter's write
      kr0 = *(const bf16x8*)(kp + (long)(k0 + 64) * DHEAD);
      kr1 = *(const bf16x8*)(kp + (long)(k0 + 64) * DHEAD + 8);
      vr0 = *(const bf16x8*)(vp + k0 + 64);
      vr1 = *(const bf16x8*)(vp + k0 + 64 + 8);
    }

    if (k0 <= qa + 15) {  // wave-uniform: skip fully-masked tiles
      // S^T: sc[jm] holds (kv = k0+jm*16+lq*4+r, q = myq)
      f32x4 sc[4] = {};
#pragma unroll
      for (int jm = 0; jm < 4; ++jm) {
        const int rk = (jm * 16 + lc) * 64;
        bf16x8 ak0 = *(const bf16x8*)&lK[rk + ((lq ^ xsw) * 8)];
        bf16x8 ak1 = *(const bf16x8*)&lK[rk + (((4 + lq) ^ xsw) * 8)];
        sc[jm] = __builtin_amdgcn_mfma_f32_16x16x32_bf16(ak0, aq[0], sc[jm], 0, 0, 0);
        sc[jm] = __builtin_amdgcn_mfma_f32_16x16x32_bf16(ak1, aq[1], sc[jm], 0, 0, 0);
      }

      // softmax-lite: p = exp2(score'); mask only near the diagonal
      const bool masked = (k0 + 63 > qa);
      unsigned int pb[4][2];
      float ls = 0.0f;
#pragma unroll
      for (int jm = 0; jm < 4; ++jm) {
        float e0 = exp2f(sc[jm][0]);
        float e1 = exp2f(sc[jm][1]);
        float e2 = exp2f(sc[jm][2]);
        float e3 = exp2f(sc[jm][3]);
        if (masked) {
          int kv = k0 + jm * 16 + lq * 4;
          e0 = (kv + 0 > myq) ? 0.0f : e0;
          e1 = (kv + 1 > myq) ? 0.0f : e1;
          e2 = (kv + 2 > myq) ? 0.0f : e2;
          e3 = (kv + 3 > myq) ? 0.0f : e3;
        }
        ls += (e0 + e1) + (e2 + e3);
        pb[jm][0] = pk2(e1, e0);
        pb[jm][1] = pk2(e3, e2);
      }
      lsum += ls;

      // V A-operand frags
      bf16x8 av[4][2];
#pragma unroll
      for (int jd = 0; jd < 4; ++jd) {
        const int rv = (jd * 16 + lc) * 64;
        av[jd][0] = *(const bf16x8*)&lV[rv + ((lq ^ xsw) * 8)];
        av[jd][1] = *(const bf16x8*)&lV[rv + (((4 + lq) ^ xsw) * 8)];
      }

      // O^T += V^T · P^T in two 32-kv halves through the wave-private lP
#pragma unroll
      for (int hh = 0; hh < 2; ++hh) {
        *(uint2*)&myP[lc * 40 + lq * 4] =
            make_uint2(pb[hh * 2][0], pb[hh * 2][1]);
        *(uint2*)&myP[lc * 40 + 16 + lq * 4] =
            make_uint2(pb[hh * 2 + 1][0], pb[hh * 2 + 1][1]);
        bf16x8 bp = *(const bf16x8*)&myP[lc * 40 + lq * 8];
#pragma unroll
        for (int jd = 0; jd < 4; ++jd)
          o_acc[jd] = __builtin_amdgcn_mfma_f32_16x16x32_bf16(av[jd][hh], bp, o_acc[jd], 0, 0, 0);
      }
    }
    __syncthreads();  // all frag reads done before next iter's LDS overwrite
  }

  // final l reduction across the 4 quads sharing q=lc
  lsum += __shfl_xor(lsum, 16, 64);
  lsum += __shfl_xor(lsum, 32, 64);
  float inv = 1.0f / lsum;

  // epilogue: ctx[b, q=myq, h*64 + dh], dh = jd*16 + lq*4 + r  (8B stores)
  u16* cp = ctx + ((long)(b * S_LEN + myq)) * DMODEL + h * DHEAD;
#pragma unroll
  for (int jd = 0; jd < 4; ++jd) {
    u16x4 ov;
#pragma unroll
    for (int r = 0; r < 4; ++r) ov[r] = f2b(o_acc[jd][r] * inv);
    *(u16x4*)&cp[jd * 16 + lq * 4] = ov;
  }
}

// ---------------------------------------------------------------------------
// ws layout (u16 elems): wt[4M] | Q[8M] | Vt[8M] | xc-then-ctx[8M] | flag
//   = 56 MB + 4 B.   K rides in d_out until the final GEMM overwrites it.
// wt layout: wtq|wtk|wtv contiguous = the [3072,1024] fused-QKV Bt; wto after.
// ---------------------------------------------------------------------------
extern "C" void kernel_launch(void* const* d_in, const int* in_sizes, int n_in,
                              void* d_out, int out_size, void* d_ws, size_t ws_size,
                              hipStream_t stream) {
  const void* x  = d_in[0];
  const void* Wq = d_in[1];
  const void* Wk = d_in[2];
  const void* Wv = d_in[3];
  const void* Wo = d_in[4];
  const void* bo = d_in[5];
  u16* ws = (u16*)d_ws;

  u16* wt  = ws;                        // 4 * 1,048,576
  u16* wto = wt + 3145728;
  u16* Qb  = ws + 4194304;              // 8,388,608
  u16* Vtb = ws + 12582912;             // 8,388,608
  u16* xc  = ws + 20971520;             // 8,388,608 (reused as ctx after QKV)
  u16* ctx = xc;
  int* flag = (int*)(ws + 29360128);
  u16* Kb  = (u16*)d_out;               // bf16 K scratch in d_out (16 MB)

  detect_dtype<<<1, 256, 0, stream>>>((const unsigned int*)x, flag);
  convert_x<<<8192, 256, 0, stream>>>(x, xc, flag);
  transpose4<<<dim3(32, 32, 4), dim3(32, 8), 0, stream>>>(Wq, Wk, Wv, Wo, wt, flag);

  gemm_qkv<<<dim3(3 * DMODEL / BN, MTOK / BM), 256, 0, stream>>>(xc, wt, Qb, Kb, Vtb);

  flash_attn<<<dim3(S_LEN / 64, NH, BATCH), 256, 0, stream>>>(Qb, Kb, Vtb, ctx);

  gemm_out<<<dim3(DMODEL / BN, MTOK / BM), 256, 0, stream>>>(ctx, wto, bo, d_out, flag);
}